// Round 9
// baseline (318.907 us; speedup 1.0000x reference)
//
#include <hip/hip_runtime.h>

#define CCH 128
#define WPAD 136   // LDS row stride in ushorts (272B)
typedef unsigned short ushort;
typedef __attribute__((ext_vector_type(8))) short bf16x8_t;
typedef __attribute__((ext_vector_type(4))) float f32x4;

union ABu { bf16x8_t v; ushort u[8]; uint4 q; };

__device__ __forceinline__ ushort f2b(float f) {   // fp32 -> bf16 RNE
  union { float f; unsigned u; } v{f};
  unsigned r = v.u + 0x7fffu + ((v.u >> 16) & 1u);
  return (ushort)(r >> 16);
}
__device__ __forceinline__ float b2f(ushort s) {
  union { unsigned u; float f; } v{(unsigned)s << 16};
  return v.f;
}

// ================= pre: weight conv + histogram (dtype self-detect) =================
__global__ __launch_bounds__(256) void k_pre(const float* __restrict__ w1a,
                                             const float* __restrict__ w1b,
                                             const float* __restrict__ w2a,
                                             const float* __restrict__ w2b,
                                             ushort* __restrict__ Wcat1, ushort* __restrict__ Wb1,
                                             ushort* __restrict__ Wcat2, ushort* __restrict__ Wb2,
                                             const void* __restrict__ ei, int* __restrict__ deg,
                                             int E) {
  const int b = blockIdx.x, t = threadIdx.x;
  if (b < 128) {
    int i = b * 256 + t;
    int c = i >> 7, k = i & 127;
    float v = (c < 128) ? w1a[c * 256 + k] - w1a[c * 256 + 128 + k]
                        : w1a[(c - 128) * 256 + 128 + k];
    Wcat1[i] = f2b(v);
    if (i < 16384) Wb1[i] = f2b(w1b[i]);
  } else if (b < 256) {
    int i = (b - 128) * 256 + t;
    int c = i >> 7, k = i & 127;
    float v = (c < 128) ? w2a[c * 256 + k] - w2a[c * 256 + 128 + k]
                        : w2a[(c - 128) * 256 + 128 + k];
    Wcat2[i] = f2b(v);
    if (i < 16384) Wb2[i] = f2b(w2b[i]);
  } else {
    __shared__ int nz;
    if (t == 0) nz = 0;
    __syncthreads();
    int e = (b - 256) * 256 + t;
    unsigned hi = (e < E) ? ((const unsigned*)ei)[2 * (size_t)e + 1] : 0u;
    if (hi) atomicAdd(&nz, 1);
    __syncthreads();
    bool i64 = (nz == 0);
    if (e < E) {
      int d = i64 ? (int)((const long long*)ei)[(size_t)E + e]
                  : ((const int*)ei)[(size_t)E + e];
      atomicAdd(&deg[d], 1);
    }
  }
}

// ================= rowptr: fused scan2+scan3, also seeds cnt = rowptr =================
__global__ __launch_bounds__(256) void k_rowptr(const int* __restrict__ deg,
                                                const int* __restrict__ bsum,
                                                int* __restrict__ rowptr,
                                                int* __restrict__ cnt,
                                                int n, int nb, int Etot) {
  __shared__ int s[256];
  const int t = threadIdx.x, b = blockIdx.x;
  s[t] = (t < nb && t < b) ? bsum[t] : 0;
  __syncthreads();
  for (int off = 128; off > 0; off >>= 1) {
    if (t < off) s[t] += s[t + off];
    __syncthreads();
  }
  int boffset = s[0];
  __syncthreads();
  int i = b * 256 + t;
  int v = (i < n) ? deg[i] : 0;
  s[t] = v; __syncthreads();
  for (int off = 1; off < 256; off <<= 1) {
    int tv = (t >= off) ? s[t - off] : 0;
    __syncthreads();
    s[t] += tv;
    __syncthreads();
  }
  if (i < n) {
    int rp = boffset + s[t] - v;
    rowptr[i] = rp;
    cnt[i] = rp;
  }
  if (b == gridDim.x - 1 && t == 0) rowptr[n] = Etot;
}

// ================= scatter: pos = atomicAdd(cnt[d]) (cnt pre-seeded with rowptr) =========
__global__ __launch_bounds__(256) void k_scatter(const void* __restrict__ ei,
                                                 int* __restrict__ cnt,
                                                 int* __restrict__ esrc, int E) {
  __shared__ int nz;
  const int t = threadIdx.x;
  if (t == 0) nz = 0;
  __syncthreads();
  int e = blockIdx.x * 256 + t;
  unsigned hi = (e < E) ? ((const unsigned*)ei)[2 * (size_t)e + 1] : 0u;
  if (hi) atomicAdd(&nz, 1);
  __syncthreads();
  bool i64 = (nz == 0);
  if (e < E) {
    int d, sv;
    if (i64) {
      sv = (int)((const long long*)ei)[(size_t)e];
      d  = (int)((const long long*)ei)[(size_t)E + e];
    } else {
      sv = ((const int*)ei)[(size_t)e];
      d  = ((const int*)ei)[(size_t)E + e];
    }
    int pos = atomicAdd(&cnt[d], 1);
    esrc[pos] = sv;
  }
}

// ================= shared GEMM pieces =================
__device__ __forceinline__ void stage_w(const ushort* __restrict__ Wp,
                                        ushort* __restrict__ wlds, int t) {
  for (int i = t; i < 128 * 16; i += 256) {
    int row = i >> 4, ch = i & 15;
    *(uint4*)&wlds[row * WPAD + ch * 8] = *(const uint4*)&Wp[row * CCH + ch * 8];
  }
}

__device__ __forceinline__ void mfma8(const ABu a[4], const ushort* __restrict__ wlds,
                                      int ln, int quad, f32x4 acc[8]) {
#pragma unroll
  for (int s = 0; s < 8; ++s) acc[s] = (f32x4){0.f, 0.f, 0.f, 0.f};
#pragma unroll
  for (int s = 0; s < 8; ++s) {
#pragma unroll
    for (int kk = 0; kk < 4; ++kk) {
      ABu b;
      b.q = *(const uint4*)&wlds[(s * 16 + ln) * WPAD + kk * 32 + quad * 8];
      acc[s] = __builtin_amdgcn_mfma_f32_16x16x32_bf16(a[kk].v, b.v, acc[s], 0, 0, 0);
    }
  }
}

__device__ __forceinline__ void epi0(f32x4 acc[8], int rowb, int ln, int quad, int nN,
                                     const float* bias, int half, ushort* dst) {
#pragma unroll
  for (int s = 0; s < 8; ++s) {
    int col = s * 16 + ln;
    float bv = half ? 0.f : bias[col];
#pragma unroll
    for (int r = 0; r < 4; ++r) {
      int row = rowb + quad * 4 + r;
      if (row < nN) dst[(size_t)row * CCH + col] = f2b(acc[s][r] + bv);
    }
  }
}

// ---------------- mix1: layer-1 EPI0 GEMM (f32 X, dual-tile) + scan1 ----------------
__global__ __launch_bounds__(256) void k_mix1(const float* __restrict__ X,
                                              const ushort* __restrict__ Wcat,
                                              const float* __restrict__ bias,
                                              ushort* __restrict__ A1,
                                              ushort* __restrict__ A2, int nN,
                                              const int* __restrict__ deg,
                                              int* __restrict__ bsum, int gH, int n) {
  __shared__ ushort wlds[128 * WPAD];
  const int t = threadIdx.x;
  if ((int)blockIdx.x >= 2 * gH) {   // ---- scan1 ----
    int* s = (int*)wlds;
    int bb = blockIdx.x - 2 * gH;
    int i = bb * 256 + t;
    s[t] = (i < n) ? deg[i] : 0;
    __syncthreads();
    for (int off = 128; off > 0; off >>= 1) {
      if (t < off) s[t] += s[t + off];
      __syncthreads();
    }
    if (t == 0) bsum[bb] = s[0];
    return;
  }
  const int half = (int)blockIdx.x >= gH;
  const int bx = half ? blockIdx.x - gH : blockIdx.x;
  stage_w(Wcat + (size_t)half * 128 * CCH, wlds, t);
  __syncthreads();
  const int wave = t >> 6, lane = t & 63;
  const int ln = lane & 15, quad = lane >> 4;
  const int rowb = bx * 128 + wave * 32;

  ABu a0[4], a1[4];
#pragma unroll
  for (int kk = 0; kk < 4; ++kk) {
    auto ldc = [&](int r, ABu& d) {
      if (r < nN) {
        const float* xp = X + (size_t)r * CCH + kk * 32 + quad * 8;
        float4 f0 = *(const float4*)xp;
        float4 f1 = *(const float4*)(xp + 4);
        d.u[0] = f2b(f0.x); d.u[1] = f2b(f0.y); d.u[2] = f2b(f0.z); d.u[3] = f2b(f0.w);
        d.u[4] = f2b(f1.x); d.u[5] = f2b(f1.y); d.u[6] = f2b(f1.z); d.u[7] = f2b(f1.w);
      } else d.q = make_uint4(0, 0, 0, 0);
    };
    ldc(rowb + ln, a0[kk]); ldc(rowb + 16 + ln, a1[kk]);
  }
  f32x4 acc[8];
  ushort* dst = half ? A2 : A1;
  mfma8(a0, wlds, ln, quad, acc);
  epi0(acc, rowb, ln, quad, nN, bias, half, dst);
  mfma8(a1, wlds, ln, quad, acc);
  epi0(acc, rowb + 16, ln, quad, nN, bias, half, dst);
}

// ---------------- fuse2: H = l2norm(relu(M@Wb1^T + deg*bb)) in-reg; A1|A2 = H@Wcat2^T ----
__global__ __launch_bounds__(256) void k_fuse2(const ushort* __restrict__ M,
                                               const ushort* __restrict__ Wb,
                                               const float* __restrict__ bb,
                                               const int* __restrict__ deg,
                                               const ushort* __restrict__ Wcat,
                                               const float* __restrict__ ba2,
                                               ushort* __restrict__ A1,
                                               ushort* __restrict__ A2, int nN) {
  __shared__ ushort wlds[128 * WPAD];      // 34816 B, restaged 3x
  __shared__ ushort hs[4 * 16 * WPAD];     // 17408 B, wave-private H tiles
  const int t = threadIdx.x;
  const int wave = t >> 6, lane = t & 63;
  const int ln = lane & 15, quad = lane >> 4;
  const int rowb = blockIdx.x * 64 + wave * 16;
  ushort* hw = &hs[wave * 16 * WPAD];

  // ---- phase 1: H tile ----
  stage_w(Wb, wlds, t);
  __syncthreads();
  {
    const int arow = rowb + ln;
    ABu a[4];
#pragma unroll
    for (int kk = 0; kk < 4; ++kk)
      a[kk].q = (arow < nN) ? *(const uint4*)(M + (size_t)arow * CCH + kk * 32 + quad * 8)
                            : make_uint4(0, 0, 0, 0);
    f32x4 acc[8];
    mfma8(a, wlds, ln, quad, acc);
    float biasv[8];
#pragma unroll
    for (int s = 0; s < 8; ++s) biasv[s] = bb[s * 16 + ln];
#pragma unroll
    for (int r = 0; r < 4; ++r) {
      int row = rowb + quad * 4 + r;
      float dn = (row < nN) ? (float)deg[row] : 0.f;
      float vals[8];
      float ss = 0.f;
#pragma unroll
      for (int s = 0; s < 8; ++s) {
        float v = fmaxf(acc[s][r] + dn * biasv[s], 0.f);
        vals[s] = v;
        ss += v * v;
      }
      ss += __shfl_xor(ss, 1, 64);
      ss += __shfl_xor(ss, 2, 64);
      ss += __shfl_xor(ss, 4, 64);
      ss += __shfl_xor(ss, 8, 64);
      float inv = 1.0f / fmaxf(sqrtf(ss), 1e-12f);
      int lr = quad * 4 + r;
#pragma unroll
      for (int s = 0; s < 8; ++s) hw[lr * WPAD + s * 16 + ln] = f2b(vals[s] * inv);
    }
  }
  // C-layout -> A-layout through wave-private LDS (same-wave RAW: compiler waits lgkmcnt)
  ABu ha[4];
#pragma unroll
  for (int kk = 0; kk < 4; ++kk)
    ha[kk].q = *(const uint4*)&hw[ln * WPAD + kk * 32 + quad * 8];

  // ---- phase 2: A1 (col half 0) ----
  __syncthreads();                         // all Wb reads done
  stage_w(Wcat, wlds, t);
  __syncthreads();
  f32x4 acc[8];
  mfma8(ha, wlds, ln, quad, acc);
  epi0(acc, rowb, ln, quad, nN, ba2, 0, A1);

  // ---- phase 3: A2 (col half 1) ----
  __syncthreads();
  stage_w(Wcat + (size_t)128 * CCH, wlds, t);
  __syncthreads();
  mfma8(ha, wlds, ln, quad, acc);
  epi0(acc, rowb, ln, quad, nN, ba2, 1, A2);
}

// ---------------- final GEMM: OUT = M@Wb2^T + deg*bias (f32) ----------------
__global__ __launch_bounds__(256) void k_gemm2(const ushort* __restrict__ M,
                                               const ushort* __restrict__ W,
                                               const float* __restrict__ bias,
                                               const int* __restrict__ deg,
                                               float* __restrict__ OUT, int nN) {
  __shared__ ushort wlds[128 * WPAD];
  const int t = threadIdx.x;
  stage_w(W, wlds, t);
  __syncthreads();
  const int wave = t >> 6, lane = t & 63;
  const int ln = lane & 15, quad = lane >> 4;
  const int rowb = blockIdx.x * 128 + wave * 32;

  ABu a0[4], a1[4];
#pragma unroll
  for (int kk = 0; kk < 4; ++kk) {
    int r0 = rowb + ln, r1 = rowb + 16 + ln;
    a0[kk].q = (r0 < nN) ? *(const uint4*)(M + (size_t)r0 * CCH + kk * 32 + quad * 8)
                         : make_uint4(0, 0, 0, 0);
    a1[kk].q = (r1 < nN) ? *(const uint4*)(M + (size_t)r1 * CCH + kk * 32 + quad * 8)
                         : make_uint4(0, 0, 0, 0);
  }
  float biasv[8];
#pragma unroll
  for (int s = 0; s < 8; ++s) biasv[s] = bias[s * 16 + ln];

  f32x4 acc[8];
  auto epi = [&](f32x4* ac, int rb) {
#pragma unroll
    for (int r = 0; r < 4; ++r) {
      int row = rb + quad * 4 + r;
      if (row >= nN) continue;
      float dn = (float)deg[row];
#pragma unroll
      for (int s = 0; s < 8; ++s)
        OUT[(size_t)row * CCH + s * 16 + ln] = ac[s][r] + dn * biasv[s];
    }
  };
  mfma8(a0, wlds, ln, quad, acc); epi(acc, rowb);
  mfma8(a1, wlds, ln, quad, acc); epi(acc, rowb + 16);
}

// ---------------- edge aggregation v4 ----------------
__global__ __launch_bounds__(256) void k_aggr(const ushort* __restrict__ A1,
                                              const ushort* __restrict__ A2,
                                              const int* __restrict__ rowptr,
                                              const int* __restrict__ esrc,
                                              const float* __restrict__ g,
                                              const float* __restrict__ be,
                                              const float* __restrict__ rm,
                                              const float* __restrict__ rv,
                                              ushort* __restrict__ M, int nNodes) {
  int node = blockIdx.x * 4 + (threadIdx.x >> 6);
  if (node >= nNodes) return;
  int lane = threadIdx.x & 63;
  int q = lane >> 4;
  int c = (lane & 15) * 8;

  uint4 aq = *(const uint4*)&A1[(size_t)node * CCH + c];
  float a[8] = {b2f((ushort)aq.x), b2f((ushort)(aq.x >> 16)),
                b2f((ushort)aq.y), b2f((ushort)(aq.y >> 16)),
                b2f((ushort)aq.z), b2f((ushort)(aq.z >> 16)),
                b2f((ushort)aq.w), b2f((ushort)(aq.w >> 16))};
  int r0 = rowptr[node], r1 = rowptr[node + 1];
  float s[8] = {0.f, 0.f, 0.f, 0.f, 0.f, 0.f, 0.f, 0.f};

  auto acc8 = [&](uint4 w) {
    const unsigned* p = (const unsigned*)&w;
#pragma unroll
    for (int j = 0; j < 4; ++j) {
      s[2*j]   += fmaxf(a[2*j]   + b2f((ushort)p[j]), 0.f);
      s[2*j+1] += fmaxf(a[2*j+1] + b2f((ushort)(p[j] >> 16)), 0.f);
    }
  };

  for (int base = r0; base < r1; base += 64) {
    int navail = r1 - base; if (navail > 64) navail = 64;
    int myi = (lane < navail) ? esrc[base + lane] : 0;
    int g4 = navail >> 2, tail = navail & 3;
    int j = 0;
    for (; j + 4 <= g4; j += 4) {
      int p0 = j * 4 + q;
      int i0 = __shfl(myi, p0, 64);
      int i1 = __shfl(myi, p0 + 4, 64);
      int i2 = __shfl(myi, p0 + 8, 64);
      int i3 = __shfl(myi, p0 + 12, 64);
      uint4 w0 = *(const uint4*)&A2[(size_t)i0 * CCH + c];
      uint4 w1 = *(const uint4*)&A2[(size_t)i1 * CCH + c];
      uint4 w2 = *(const uint4*)&A2[(size_t)i2 * CCH + c];
      uint4 w3 = *(const uint4*)&A2[(size_t)i3 * CCH + c];
      acc8(w0); acc8(w1); acc8(w2); acc8(w3);
    }
    for (; j < g4; ++j) {
      int i0 = __shfl(myi, j * 4 + q, 64);
      acc8(*(const uint4*)&A2[(size_t)i0 * CCH + c]);
    }
    int pt = g4 * 4 + q; if (pt > 63) pt = 63;
    int it = __shfl(myi, pt, 64);
    if (q < tail) acc8(*(const uint4*)&A2[(size_t)it * CCH + c]);
  }
#pragma unroll
  for (int j = 0; j < 8; ++j) {
    s[j] += __shfl_xor(s[j], 16, 64);
    s[j] += __shfl_xor(s[j], 32, 64);
  }

  if (q == 0) {
    float dn = (float)(r1 - r0);
    unsigned p[4];
#pragma unroll
    for (int j = 0; j < 4; ++j) {
      float sc0 = g[c + 2*j]     * rsqrtf(rv[c + 2*j]     + 1e-5f);
      float sc1 = g[c + 2*j + 1] * rsqrtf(rv[c + 2*j + 1] + 1e-5f);
      float o0 = sc0 * s[2*j]     + dn * (be[c + 2*j]     - rm[c + 2*j]     * sc0);
      float o1 = sc1 * s[2*j + 1] + dn * (be[c + 2*j + 1] - rm[c + 2*j + 1] * sc1);
      p[j] = (unsigned)f2b(o0) | ((unsigned)f2b(o1) << 16);
    }
    *(uint4*)&M[(size_t)node * CCH + c] = make_uint4(p[0], p[1], p[2], p[3]);
  }
}

// ---------------- launch ----------------
extern "C" void kernel_launch(void* const* d_in, const int* in_sizes, int n_in,
                              void* d_out, int out_size, void* d_ws, size_t ws_size,
                              hipStream_t stream) {
  const float* x   = (const float*)d_in[0];
  const void*  ei  = d_in[1];
  const float* w1a = (const float*)d_in[2];
  const float* b1a = (const float*)d_in[3];
  const float* g1  = (const float*)d_in[4];
  const float* be1 = (const float*)d_in[5];
  const float* rm1 = (const float*)d_in[6];
  const float* rv1 = (const float*)d_in[7];
  const float* w1b = (const float*)d_in[8];
  const float* b1b = (const float*)d_in[9];
  const float* w2a = (const float*)d_in[10];
  const float* b2a = (const float*)d_in[11];
  const float* g2  = (const float*)d_in[12];
  const float* be2 = (const float*)d_in[13];
  const float* rm2 = (const float*)d_in[14];
  const float* rv2 = (const float*)d_in[15];
  const float* w2b = (const float*)d_in[16];
  const float* b2b = (const float*)d_in[17];

  const int N = in_sizes[0] / CCH;   // 50000
  const int E = in_sizes[1] / 2;     // 600000
  const size_t NC = (size_t)N * CCH;

  int* deg    = (int*)d_ws;              // N
  int* cnt    = deg + N;                 // N
  int* rowptr = cnt + N;                 // N+1
  int* bsum   = rowptr + N + 1;          // 256
  int* esrc   = bsum + 256;              // E
  uintptr_t pw = ((uintptr_t)(esrc + E) + 63) & ~(uintptr_t)63;
  ushort* Wcat1 = (ushort*)pw;
  ushort* Wcat2 = Wcat1 + 32768;
  ushort* Wb1   = Wcat2 + 32768;
  ushort* Wb2   = Wb1 + 16384;
  uintptr_t pb = ((uintptr_t)(Wb2 + 16384) + 63) & ~(uintptr_t)63;
  ushort* B0 = (ushort*)pb;              // NC bf16 (A1)
  ushort* B1 = B0 + NC;                  // NC bf16 (A2)
  ushort* MB = B1 + NC;                  // NC bf16 (M)

  const int gE  = (E + 255) / 256;       // 2344
  const int gS  = (N + 255) / 256;       // 196
  const int gH  = (N + 127) / 128;       // 391
  const int gF  = (N + 63) / 64;         // 782
  const int gA  = (N + 3) / 4;           // 12500

  hipMemsetAsync(deg, 0, sizeof(int) * (size_t)N, stream);
  k_pre<<<256 + gE, 256, 0, stream>>>(w1a, w1b, w2a, w2b,
                                      Wcat1, Wb1, Wcat2, Wb2, ei, deg, E);
  k_mix1<<<2 * gH + gS, 256, 0, stream>>>(x, Wcat1, b1a, B0, B1, N, deg, bsum, gH, N);
  k_rowptr<<<gS, 256, 0, stream>>>(deg, bsum, rowptr, cnt, N, gS, E);
  k_scatter<<<gE, 256, 0, stream>>>(ei, cnt, esrc, E);

  k_aggr<<<gA, 256, 0, stream>>>(B0, B1, rowptr, esrc, g1, be1, rm1, rv1, MB, N);
  k_fuse2<<<gF, 256, 0, stream>>>(MB, Wb1, b1b, deg, Wcat2, b2a, B0, B1, N);
  k_aggr<<<gA, 256, 0, stream>>>(B0, B1, rowptr, esrc, g2, be2, rm2, rv2, MB, N);
  k_gemm2<<<gH, 256, 0, stream>>>(MB, Wb2, b2b, deg, (float*)d_out, N);
}

// Round 10
// 305.146 us; speedup vs baseline: 1.0451x; 1.0451x over previous
//
#include <hip/hip_runtime.h>

#define CCH 128
#define WPAD 136   // LDS row stride in ushorts (272B)
typedef unsigned short ushort;
typedef __attribute__((ext_vector_type(8))) short bf16x8_t;
typedef __attribute__((ext_vector_type(4))) float f32x4;

union ABu { bf16x8_t v; ushort u[8]; uint4 q; };

__device__ __forceinline__ ushort f2b(float f) {   // fp32 -> bf16 RNE
  union { float f; unsigned u; } v{f};
  unsigned r = v.u + 0x7fffu + ((v.u >> 16) & 1u);
  return (ushort)(r >> 16);
}
__device__ __forceinline__ float b2f(ushort s) {
  union { unsigned u; float f; } v{(unsigned)s << 16};
  return v.f;
}

// ================= pre: weight conv + histogram (dtype self-detect) =================
__global__ __launch_bounds__(256) void k_pre(const float* __restrict__ w1a,
                                             const float* __restrict__ w1b,
                                             const float* __restrict__ w2a,
                                             const float* __restrict__ w2b,
                                             ushort* __restrict__ Wcat1, ushort* __restrict__ Wb1,
                                             ushort* __restrict__ Wcat2, ushort* __restrict__ Wb2,
                                             const void* __restrict__ ei, int* __restrict__ deg,
                                             int E) {
  const int b = blockIdx.x, t = threadIdx.x;
  if (b < 128) {
    int i = b * 256 + t;
    int c = i >> 7, k = i & 127;
    float v = (c < 128) ? w1a[c * 256 + k] - w1a[c * 256 + 128 + k]
                        : w1a[(c - 128) * 256 + 128 + k];
    Wcat1[i] = f2b(v);
    if (i < 16384) Wb1[i] = f2b(w1b[i]);
  } else if (b < 256) {
    int i = (b - 128) * 256 + t;
    int c = i >> 7, k = i & 127;
    float v = (c < 128) ? w2a[c * 256 + k] - w2a[c * 256 + 128 + k]
                        : w2a[(c - 128) * 256 + 128 + k];
    Wcat2[i] = f2b(v);
    if (i < 16384) Wb2[i] = f2b(w2b[i]);
  } else {
    __shared__ int nz;
    if (t == 0) nz = 0;
    __syncthreads();
    int e = (b - 256) * 256 + t;
    unsigned hi = (e < E) ? ((const unsigned*)ei)[2 * (size_t)e + 1] : 0u;
    if (hi) atomicAdd(&nz, 1);
    __syncthreads();
    bool i64 = (nz == 0);
    if (e < E) {
      int d = i64 ? (int)((const long long*)ei)[(size_t)E + e]
                  : ((const int*)ei)[(size_t)E + e];
      atomicAdd(&deg[d], 1);
    }
  }
}

// ================= scan1: per-block sums of deg =================
__global__ __launch_bounds__(256) void k_scan1(const int* __restrict__ deg,
                                               int* __restrict__ bsum, int n) {
  __shared__ int s[256];
  int t = threadIdx.x, i = blockIdx.x * 256 + t;
  s[t] = (i < n) ? deg[i] : 0;
  __syncthreads();
  for (int off = 128; off > 0; off >>= 1) {
    if (t < off) s[t] += s[t + off];
    __syncthreads();
  }
  if (t == 0) bsum[blockIdx.x] = s[0];
}

// ================= rowptr: fused scan2+scan3, seeds cnt = rowptr =================
__global__ __launch_bounds__(256) void k_rowptr(const int* __restrict__ deg,
                                                const int* __restrict__ bsum,
                                                int* __restrict__ rowptr,
                                                int* __restrict__ cnt,
                                                int n, int nb, int Etot) {
  __shared__ int s[256];
  const int t = threadIdx.x, b = blockIdx.x;
  s[t] = (t < nb && t < b) ? bsum[t] : 0;
  __syncthreads();
  for (int off = 128; off > 0; off >>= 1) {
    if (t < off) s[t] += s[t + off];
    __syncthreads();
  }
  int boffset = s[0];
  __syncthreads();
  int i = b * 256 + t;
  int v = (i < n) ? deg[i] : 0;
  s[t] = v; __syncthreads();
  for (int off = 1; off < 256; off <<= 1) {
    int tv = (t >= off) ? s[t - off] : 0;
    __syncthreads();
    s[t] += tv;
    __syncthreads();
  }
  if (i < n) {
    int rp = boffset + s[t] - v;
    rowptr[i] = rp;
    cnt[i] = rp;
  }
  if (b == gridDim.x - 1 && t == 0) rowptr[n] = Etot;
}

// ================= shared GEMM pieces =================
__device__ __forceinline__ void stage_w(const ushort* __restrict__ Wp,
                                        ushort* __restrict__ wlds, int t) {
  for (int i = t; i < 128 * 16; i += 256) {
    int row = i >> 4, ch = i & 15;
    *(uint4*)&wlds[row * WPAD + ch * 8] = *(const uint4*)&Wp[row * CCH + ch * 8];
  }
}

__device__ __forceinline__ void mfma8(const ABu a[4], const ushort* __restrict__ wlds,
                                      int ln, int quad, f32x4 acc[8]) {
#pragma unroll
  for (int s = 0; s < 8; ++s) acc[s] = (f32x4){0.f, 0.f, 0.f, 0.f};
#pragma unroll
  for (int s = 0; s < 8; ++s) {
#pragma unroll
    for (int kk = 0; kk < 4; ++kk) {
      ABu b;
      b.q = *(const uint4*)&wlds[(s * 16 + ln) * WPAD + kk * 32 + quad * 8];
      acc[s] = __builtin_amdgcn_mfma_f32_16x16x32_bf16(a[kk].v, b.v, acc[s], 0, 0, 0);
    }
  }
}

__device__ __forceinline__ void epi0(f32x4 acc[8], int rowb, int ln, int quad, int nN,
                                     const float* bias, int half, ushort* dst) {
#pragma unroll
  for (int s = 0; s < 8; ++s) {
    int col = s * 16 + ln;
    float bv = half ? 0.f : bias[col];
#pragma unroll
    for (int r = 0; r < 4; ++r) {
      int row = rowb + quad * 4 + r;
      if (row < nN) dst[(size_t)row * CCH + col] = f2b(acc[s][r] + bv);
    }
  }
}

// ---------------- mix: layer-1 EPI0 GEMM (f32 X, dual-tile) + scatter overlapped ----------
__global__ __launch_bounds__(256) void k_mix(const float* __restrict__ X,
                                             const ushort* __restrict__ Wcat,
                                             const float* __restrict__ bias,
                                             ushort* __restrict__ A1,
                                             ushort* __restrict__ A2, int nN,
                                             const void* __restrict__ ei,
                                             int* __restrict__ cnt,
                                             int* __restrict__ esrc, int E, int gH) {
  __shared__ ushort wlds[128 * WPAD];
  const int t = threadIdx.x;
  if ((int)blockIdx.x >= 2 * gH) {   // ---- scatter blocks (overlap with GEMM waves) ----
    int* nzp = (int*)wlds;
    if (t == 0) nzp[0] = 0;
    __syncthreads();
    int e = ((int)blockIdx.x - 2 * gH) * 256 + t;
    unsigned hi = (e < E) ? ((const unsigned*)ei)[2 * (size_t)e + 1] : 0u;
    if (hi) atomicAdd(nzp, 1);
    __syncthreads();
    bool i64 = (nzp[0] == 0);
    if (e < E) {
      int d, sv;
      if (i64) {
        sv = (int)((const long long*)ei)[(size_t)e];
        d  = (int)((const long long*)ei)[(size_t)E + e];
      } else {
        sv = ((const int*)ei)[(size_t)e];
        d  = ((const int*)ei)[(size_t)E + e];
      }
      int pos = atomicAdd(&cnt[d], 1);
      esrc[pos] = sv;
    }
    return;
  }
  const int half = (int)blockIdx.x >= gH;
  const int bx = half ? blockIdx.x - gH : blockIdx.x;
  stage_w(Wcat + (size_t)half * 128 * CCH, wlds, t);
  __syncthreads();
  const int wave = t >> 6, lane = t & 63;
  const int ln = lane & 15, quad = lane >> 4;
  const int rowb = bx * 128 + wave * 32;

  ABu a0[4], a1[4];
#pragma unroll
  for (int kk = 0; kk < 4; ++kk) {
    auto ldc = [&](int r, ABu& d) {
      if (r < nN) {
        const float* xp = X + (size_t)r * CCH + kk * 32 + quad * 8;
        float4 f0 = *(const float4*)xp;
        float4 f1 = *(const float4*)(xp + 4);
        d.u[0] = f2b(f0.x); d.u[1] = f2b(f0.y); d.u[2] = f2b(f0.z); d.u[3] = f2b(f0.w);
        d.u[4] = f2b(f1.x); d.u[5] = f2b(f1.y); d.u[6] = f2b(f1.z); d.u[7] = f2b(f1.w);
      } else d.q = make_uint4(0, 0, 0, 0);
    };
    ldc(rowb + ln, a0[kk]); ldc(rowb + 16 + ln, a1[kk]);
  }
  f32x4 acc[8];
  ushort* dst = half ? A2 : A1;
  mfma8(a0, wlds, ln, quad, acc);
  epi0(acc, rowb, ln, quad, nN, bias, half, dst);
  mfma8(a1, wlds, ln, quad, acc);
  epi0(acc, rowb + 16, ln, quad, nN, bias, half, dst);
}

// ---------------- standalone GEMMs (round-8 shape) ----------------
// EPI 0: gridDim.y = 2 col-halves -> A1/A2. EPI 1: H = l2norm(relu(.+deg*b)). EPI 2: f32 out.
template <int EPI>
__global__ __launch_bounds__(256) void k_gemm(const ushort* __restrict__ XB,
                                              const ushort* __restrict__ W,
                                              const float* __restrict__ bias,
                                              const int* __restrict__ deg,
                                              void* __restrict__ Y1,
                                              ushort* __restrict__ Y2, int nN) {
  __shared__ ushort wlds[128 * WPAD];
  const int t = threadIdx.x;
  const int half = (EPI == 0) ? blockIdx.y : 0;
  stage_w(W + (size_t)half * 128 * CCH, wlds, t);
  __syncthreads();
  const int wave = t >> 6, lane = t & 63;
  const int ln = lane & 15, quad = lane >> 4;
  const int rowb = blockIdx.x * 128 + wave * 32;

  ABu a0[4], a1[4];
#pragma unroll
  for (int kk = 0; kk < 4; ++kk) {
    int r0 = rowb + ln, r1 = rowb + 16 + ln;
    a0[kk].q = (r0 < nN) ? *(const uint4*)(XB + (size_t)r0 * CCH + kk * 32 + quad * 8)
                         : make_uint4(0, 0, 0, 0);
    a1[kk].q = (r1 < nN) ? *(const uint4*)(XB + (size_t)r1 * CCH + kk * 32 + quad * 8)
                         : make_uint4(0, 0, 0, 0);
  }
  f32x4 acc[8];

  if constexpr (EPI == 0) {
    ushort* dst = half ? Y2 : (ushort*)Y1;
    mfma8(a0, wlds, ln, quad, acc);
    epi0(acc, rowb, ln, quad, nN, bias, half, dst);
    mfma8(a1, wlds, ln, quad, acc);
    epi0(acc, rowb + 16, ln, quad, nN, bias, half, dst);
  } else if constexpr (EPI == 1) {
    ushort* H = (ushort*)Y1;
    float biasv[8];
#pragma unroll
    for (int s = 0; s < 8; ++s) biasv[s] = bias[s * 16 + ln];
    auto epi = [&](f32x4* ac, int rb) {
#pragma unroll
      for (int r = 0; r < 4; ++r) {
        int row = rb + quad * 4 + r;
        float dn = (row < nN) ? (float)deg[row] : 0.f;
        float vals[8];
        float ss = 0.f;
#pragma unroll
        for (int s = 0; s < 8; ++s) {
          float v = fmaxf(ac[s][r] + dn * biasv[s], 0.f);
          vals[s] = v;
          ss += v * v;
        }
        ss += __shfl_xor(ss, 1, 64);
        ss += __shfl_xor(ss, 2, 64);
        ss += __shfl_xor(ss, 4, 64);
        ss += __shfl_xor(ss, 8, 64);
        float inv = 1.0f / fmaxf(sqrtf(ss), 1e-12f);
        if (row < nN) {
#pragma unroll
          for (int s = 0; s < 8; ++s)
            H[(size_t)row * CCH + s * 16 + ln] = f2b(vals[s] * inv);
        }
      }
    };
    mfma8(a0, wlds, ln, quad, acc); epi(acc, rowb);
    mfma8(a1, wlds, ln, quad, acc); epi(acc, rowb + 16);
  } else {
    float* OUT = (float*)Y1;
    float biasv[8];
#pragma unroll
    for (int s = 0; s < 8; ++s) biasv[s] = bias[s * 16 + ln];
    auto epi = [&](f32x4* ac, int rb) {
#pragma unroll
      for (int r = 0; r < 4; ++r) {
        int row = rb + quad * 4 + r;
        if (row >= nN) continue;
        float dn = (float)deg[row];
#pragma unroll
        for (int s = 0; s < 8; ++s)
          OUT[(size_t)row * CCH + s * 16 + ln] = ac[s][r] + dn * biasv[s];
      }
    };
    mfma8(a0, wlds, ln, quad, acc); epi(acc, rowb);
    mfma8(a1, wlds, ln, quad, acc); epi(acc, rowb + 16);
  }
}

// ---------------- edge aggregation v4 ----------------
__global__ __launch_bounds__(256) void k_aggr(const ushort* __restrict__ A1,
                                              const ushort* __restrict__ A2,
                                              const int* __restrict__ rowptr,
                                              const int* __restrict__ esrc,
                                              const float* __restrict__ g,
                                              const float* __restrict__ be,
                                              const float* __restrict__ rm,
                                              const float* __restrict__ rv,
                                              ushort* __restrict__ M, int nNodes) {
  int node = blockIdx.x * 4 + (threadIdx.x >> 6);
  if (node >= nNodes) return;
  int lane = threadIdx.x & 63;
  int q = lane >> 4;
  int c = (lane & 15) * 8;

  uint4 aq = *(const uint4*)&A1[(size_t)node * CCH + c];
  float a[8] = {b2f((ushort)aq.x), b2f((ushort)(aq.x >> 16)),
                b2f((ushort)aq.y), b2f((ushort)(aq.y >> 16)),
                b2f((ushort)aq.z), b2f((ushort)(aq.z >> 16)),
                b2f((ushort)aq.w), b2f((ushort)(aq.w >> 16))};
  int r0 = rowptr[node], r1 = rowptr[node + 1];
  float s[8] = {0.f, 0.f, 0.f, 0.f, 0.f, 0.f, 0.f, 0.f};

  auto acc8 = [&](uint4 w) {
    const unsigned* p = (const unsigned*)&w;
#pragma unroll
    for (int j = 0; j < 4; ++j) {
      s[2*j]   += fmaxf(a[2*j]   + b2f((ushort)p[j]), 0.f);
      s[2*j+1] += fmaxf(a[2*j+1] + b2f((ushort)(p[j] >> 16)), 0.f);
    }
  };

  for (int base = r0; base < r1; base += 64) {
    int navail = r1 - base; if (navail > 64) navail = 64;
    int myi = (lane < navail) ? esrc[base + lane] : 0;
    int g4 = navail >> 2, tail = navail & 3;
    int j = 0;
    for (; j + 4 <= g4; j += 4) {
      int p0 = j * 4 + q;
      int i0 = __shfl(myi, p0, 64);
      int i1 = __shfl(myi, p0 + 4, 64);
      int i2 = __shfl(myi, p0 + 8, 64);
      int i3 = __shfl(myi, p0 + 12, 64);
      uint4 w0 = *(const uint4*)&A2[(size_t)i0 * CCH + c];
      uint4 w1 = *(const uint4*)&A2[(size_t)i1 * CCH + c];
      uint4 w2 = *(const uint4*)&A2[(size_t)i2 * CCH + c];
      uint4 w3 = *(const uint4*)&A2[(size_t)i3 * CCH + c];
      acc8(w0); acc8(w1); acc8(w2); acc8(w3);
    }
    for (; j < g4; ++j) {
      int i0 = __shfl(myi, j * 4 + q, 64);
      acc8(*(const uint4*)&A2[(size_t)i0 * CCH + c]);
    }
    int pt = g4 * 4 + q; if (pt > 63) pt = 63;
    int it = __shfl(myi, pt, 64);
    if (q < tail) acc8(*(const uint4*)&A2[(size_t)it * CCH + c]);
  }
#pragma unroll
  for (int j = 0; j < 8; ++j) {
    s[j] += __shfl_xor(s[j], 16, 64);
    s[j] += __shfl_xor(s[j], 32, 64);
  }

  if (q == 0) {
    float dn = (float)(r1 - r0);
    unsigned p[4];
#pragma unroll
    for (int j = 0; j < 4; ++j) {
      float sc0 = g[c + 2*j]     * rsqrtf(rv[c + 2*j]     + 1e-5f);
      float sc1 = g[c + 2*j + 1] * rsqrtf(rv[c + 2*j + 1] + 1e-5f);
      float o0 = sc0 * s[2*j]     + dn * (be[c + 2*j]     - rm[c + 2*j]     * sc0);
      float o1 = sc1 * s[2*j + 1] + dn * (be[c + 2*j + 1] - rm[c + 2*j + 1] * sc1);
      p[j] = (unsigned)f2b(o0) | ((unsigned)f2b(o1) << 16);
    }
    *(uint4*)&M[(size_t)node * CCH + c] = make_uint4(p[0], p[1], p[2], p[3]);
  }
}

// ---------------- launch ----------------
extern "C" void kernel_launch(void* const* d_in, const int* in_sizes, int n_in,
                              void* d_out, int out_size, void* d_ws, size_t ws_size,
                              hipStream_t stream) {
  const float* x   = (const float*)d_in[0];
  const void*  ei  = d_in[1];
  const float* w1a = (const float*)d_in[2];
  const float* b1a = (const float*)d_in[3];
  const float* g1  = (const float*)d_in[4];
  const float* be1 = (const float*)d_in[5];
  const float* rm1 = (const float*)d_in[6];
  const float* rv1 = (const float*)d_in[7];
  const float* w1b = (const float*)d_in[8];
  const float* b1b = (const float*)d_in[9];
  const float* w2a = (const float*)d_in[10];
  const float* b2a = (const float*)d_in[11];
  const float* g2  = (const float*)d_in[12];
  const float* be2 = (const float*)d_in[13];
  const float* rm2 = (const float*)d_in[14];
  const float* rv2 = (const float*)d_in[15];
  const float* w2b = (const float*)d_in[16];
  const float* b2b = (const float*)d_in[17];

  const int N = in_sizes[0] / CCH;   // 50000
  const int E = in_sizes[1] / 2;     // 600000
  const size_t NC = (size_t)N * CCH;

  int* deg    = (int*)d_ws;              // N
  int* cnt    = deg + N;                 // N
  int* rowptr = cnt + N;                 // N+1
  int* bsum   = rowptr + N + 1;          // 256
  int* esrc   = bsum + 256;              // E
  uintptr_t pw = ((uintptr_t)(esrc + E) + 63) & ~(uintptr_t)63;
  ushort* Wcat1 = (ushort*)pw;
  ushort* Wcat2 = Wcat1 + 32768;
  ushort* Wb1   = Wcat2 + 32768;
  ushort* Wb2   = Wb1 + 16384;
  uintptr_t pb = ((uintptr_t)(Wb2 + 16384) + 63) & ~(uintptr_t)63;
  ushort* B0 = (ushort*)pb;              // NC bf16 (A1)
  ushort* B1 = B0 + NC;                  // NC bf16 (A2)
  ushort* MB = B1 + NC;                  // NC bf16 (M)
  ushort* HB = MB + NC;                  // NC bf16 (H)

  const int gE  = (E + 255) / 256;       // 2344
  const int gS  = (N + 255) / 256;       // 196
  const int gH  = (N + 127) / 128;       // 391
  const int gA  = (N + 3) / 4;           // 12500

  hipMemsetAsync(deg, 0, sizeof(int) * (size_t)N, stream);
  k_pre<<<256 + gE, 256, 0, stream>>>(w1a, w1b, w2a, w2b,
                                      Wcat1, Wb1, Wcat2, Wb2, ei, deg, E);
  k_scan1<<<gS, 256, 0, stream>>>(deg, bsum, N);
  k_rowptr<<<gS, 256, 0, stream>>>(deg, bsum, rowptr, cnt, N, gS, E);
  // layer-1 GEMM + scatter overlapped in one grid
  k_mix<<<2 * gH + gE, 256, 0, stream>>>(x, Wcat1, b1a, B0, B1, N, ei, cnt, esrc, E, gH);

  k_aggr<<<gA, 256, 0, stream>>>(B0, B1, rowptr, esrc, g1, be1, rm1, rv1, MB, N);
  k_gemm<1><<<gH, 256, 0, stream>>>(MB, Wb1, b1b, deg, HB, nullptr, N);
  k_gemm<0><<<dim3(gH, 2), 256, 0, stream>>>(HB, Wcat2, b2a, deg, B0, B1, N);
  k_aggr<<<gA, 256, 0, stream>>>(B0, B1, rowptr, esrc, g2, be2, rm2, rv2, MB, N);
  k_gemm<2><<<gH, 256, 0, stream>>>(MB, Wb2, b2b, deg, d_out, nullptr, N);
}